// Round 4
// baseline (30550.848 us; speedup 1.0000x reference)
//
#include <hip/hip_runtime.h>
#include <hip/hip_bf16.h>
#include <hip/hip_cooperative_groups.h>
#include <math.h>

namespace cg = cooperative_groups;

#define BB 256
#define SS 256
#define DIN 300
#define D2 300
#define HH 512

__device__ __forceinline__ float sigf(float x) { return 1.0f / (1.0f + expf(-x)); }

// Cross-XCD coherent accesses (bypass non-coherent per-XCD L2, served by L3).
__device__ __forceinline__ float ld_sc(const float* p) {
    return __hip_atomic_load(p, __ATOMIC_RELAXED, __HIP_MEMORY_SCOPE_AGENT);
}
__device__ __forceinline__ void st_sc(float* p, float v) {
    __hip_atomic_store(p, v, __ATOMIC_RELAXED, __HIP_MEMORY_SCOPE_AGENT);
}

// Grid barrier: fresh counter per event. __syncthreads drains vmcnt (sc1
// stores are at L3 when it retires); release-add publishes arrival.
__device__ __forceinline__ void gbar(int* cnt, int tid) {
    __syncthreads();
    if (tid == 0) {
        __hip_atomic_fetch_add(cnt, 1, __ATOMIC_RELEASE, __HIP_MEMORY_SCOPE_AGENT);
        while (__hip_atomic_load(cnt, __ATOMIC_RELAXED, __HIP_MEMORY_SCOPE_AGENT) < 256) {
            __builtin_amdgcn_s_sleep(1);
        }
    }
    __syncthreads();
}

// ---------------------------------------------------------------------------
// xp = tanh(x @ W_in + b_in), transposed to [S][B][D2].
// ---------------------------------------------------------------------------
__global__ __launch_bounds__(256) void xp_kernel(
    const float* __restrict__ A, const float* __restrict__ Bm,
    const float* __restrict__ bias, float* __restrict__ C)
{
    __shared__ float As[2][16][34];
    __shared__ float Bs[2][16][64];
    const int tid = threadIdx.x;
    const int m0 = blockIdx.y * 32;
    const int n0 = blockIdx.x * 64;
    const int tx = tid & 15;
    const int ty = tid >> 4;
    float acc[2][4] = {{0.f,0.f,0.f,0.f},{0.f,0.f,0.f,0.f}};
    const int NC = (DIN + 15) >> 4;

    float ra0, ra1, rb[4];
    auto load_regs = [&](int c) {
        const int k0 = c << 4;
        int e = tid, kk = e & 15, r = e >> 4;
        ra0 = (k0 + kk < DIN) ? A[(size_t)(m0 + r) * DIN + k0 + kk] : 0.f;
        e = tid + 256; kk = e & 15; r = e >> 4;
        ra1 = (k0 + kk < DIN) ? A[(size_t)(m0 + r) * DIN + k0 + kk] : 0.f;
#pragma unroll
        for (int i = 0; i < 4; ++i) {
            int e2 = tid + (i << 8);
            int kk2 = e2 >> 6, cc = e2 & 63;
            rb[i] = (k0 + kk2 < DIN && n0 + cc < D2) ? Bm[(k0 + kk2) * D2 + n0 + cc] : 0.f;
        }
    };
    auto store_lds = [&](int buf) {
        int e = tid; As[buf][e & 15][e >> 4] = ra0;
        e = tid + 256; As[buf][e & 15][e >> 4] = ra1;
#pragma unroll
        for (int i = 0; i < 4; ++i) {
            int e2 = tid + (i << 8);
            Bs[buf][e2 >> 6][e2 & 63] = rb[i];
        }
    };

    load_regs(0); store_lds(0);
    for (int c = 0; c < NC; ++c) {
        __syncthreads();
        if (c + 1 < NC) load_regs(c + 1);
        const int buf = c & 1;
#pragma unroll
        for (int kk = 0; kk < 16; ++kk) {
            float2 a = *(const float2*)&As[buf][kk][ty * 2];
            float4 b = *(const float4*)&Bs[buf][kk][tx * 4];
            acc[0][0] += a.x * b.x; acc[0][1] += a.x * b.y;
            acc[0][2] += a.x * b.z; acc[0][3] += a.x * b.w;
            acc[1][0] += a.y * b.x; acc[1][1] += a.y * b.y;
            acc[1][2] += a.y * b.z; acc[1][3] += a.y * b.w;
        }
        if (c + 1 < NC) store_lds((c + 1) & 1);
    }

#pragma unroll
    for (int j = 0; j < 2; ++j) {
        const int r = m0 + ty * 2 + j;
        const int b = r >> 8;
        const int s = r & 255;
#pragma unroll
        for (int i = 0; i < 4; ++i) {
            const int col = n0 + tx * 4 + i;
            if (col < D2) {
                C[((size_t)s * BB + b) * D2 + col] = tanhf(acc[j][i] + bias[col]);
            }
        }
    }
}

// ---------------------------------------------------------------------------
// Persistent scan. 256 WGs x 256 threads, 1/CU. All WGs own the SAME 16 batch
// rows (b0 = (w>>4)*16) in every phase; column slice = (w&15).
// A-operands are staged once per phase into LDS (AT); weights stream from L2
// with double buffering. 3 custom grid barriers per step.
// ---------------------------------------------------------------------------
__global__ __launch_bounds__(256, 1) void scan_kernel(
    const float* __restrict__ xp,   // [S][B][D2]
    const float* __restrict__ Q, const float* __restrict__ R,
    const float* __restrict__ Wih, const float* __restrict__ Whh,
    const float* __restrict__ bih, const float* __restrict__ bhh,
    float* __restrict__ xt2, float* __restrict__ ht, float* __restrict__ ht2,
    __hip_bfloat16* __restrict__ hseq, int* __restrict__ bars)
{
    cg::grid_group grid = cg::this_grid();
    // AT: phase A: ht[16][512] in cols 0..511.
    //     phase B: xt2[16][300] in cols 0..299 (+4 zero pad) — kept for phase C.
    //     phase C: ht2[16][512] in cols 304..815.
    __shared__ float AT[16][820];               // 52.5 KB, stride 820 (banks ok)
    __shared__ float WsA[2][16][20];            // phase A weight stream (Q slice)
    __shared__ float WsB[2][16][32];            // phase B weight stream (R slice)
    __shared__ float Bs[2][16][4][33];          // phase C weight stream

    const int w = blockIdx.x;
    const int tid = threadIdx.x;
    const int b0 = (w >> 4) * 16;       // 16 batch rows owned in ALL phases
    const int cs = w & 15;              // column-slice index
    const int n0A = cs * 19;            // phase A cols (19 wide, clipped at 300)
    const int h0  = cs * 32;            // phase B/C col slice

    // ---- init: zero ht slice (rows b0.., cols h0..h0+31), bars; ct in regs.
    {
        int e = tid * 2;                 // 512 elements
        int r = e >> 5, c = e & 31;
        st_sc(&ht[(size_t)(b0 + r) * HH + h0 + c], 0.f);
        st_sc(&ht[(size_t)(b0 + r) * HH + h0 + c + 1], 0.f);
        if (tid < 3) {
            __hip_atomic_store(&bars[w * 3 + tid], 0, __ATOMIC_RELAXED,
                               __HIP_MEMORY_SCOPE_AGENT);
        }
    }
    float ct_reg[2] = {0.f, 0.f};

    // Phase A compute mapping (one output per thread, 304 of 256... 16x19=304,
    // threads 0..303 -> but we have 256: threads 0..255 cover r=0..13; handle
    // remaining 48 outputs by letting threads 0..47 take a second output.
    const int rA = tid / 19, cA = tid % 19;          // first output
    const int rA2 = (tid + 256) / 19, cA2 = (tid + 256) % 19;  // second (tid<48)
    // Phase B mapping: 16 rows x 32 cols, 2 cols/thread
    const int rB = tid >> 4, cB2 = (tid & 15) * 2;
    // Phase C mapping
    const int hx = tid & 31;
    const int rp = tid >> 5;
    const int h = h0 + hx;
    const float bi0 = bih[h] + bhh[h];
    const float bi1 = bih[512 + h] + bhh[512 + h];
    const float bi2 = bih[1024 + h] + bhh[1024 + h];
    const float bi3 = bih[1536 + h] + bhh[1536 + h];

    grid.sync();

    for (int t = 0; t < SS; ++t) {
        const float* xpt = xp + (size_t)t * BB * D2;

        // ================= Phase A: xt2 = 2*sig(ht@Q) * xp_t =================
        // stage ht[b0..b0+15][0..511] -> AT[.][0..511]
#pragma unroll
        for (int i = 0; i < 8; ++i) {
            int e = tid + (i << 8);
            int row = e >> 7, c4 = (e & 127) << 2;
            const float* p = &ht[(size_t)(b0 + row) * HH + c4];
            float v0 = ld_sc(p), v1 = ld_sc(p + 1), v2 = ld_sc(p + 2), v3 = ld_sc(p + 3);
            AT[row][c4] = v0; AT[row][c4 + 1] = v1;
            AT[row][c4 + 2] = v2; AT[row][c4 + 3] = v3;
        }
        // prefetch aux (xp is step-private, plain load)
        float aux1 = (n0A + cA < 300) ? xpt[(b0 + rA) * D2 + n0A + cA] : 0.f;
        float aux2 = (tid < 48 && n0A + cA2 < 300) ? xpt[(b0 + rA2) * D2 + n0A + cA2] : 0.f;

        {
            float wr[2];
            auto loadW = [&](int cblk) {
                const int k0 = cblk << 4;
#pragma unroll
                for (int i = 0; i < 2; ++i) {
                    int e = tid + (i << 8);
                    wr[i] = 0.f;
                    if (e < 320) {
                        int kk = e / 20, cc = e % 20;
                        if (cc < 19 && n0A + cc < 300)
                            wr[i] = Q[(size_t)(k0 + kk) * D2 + n0A + cc];
                    }
                }
            };
            auto storeW = [&](int buf) {
#pragma unroll
                for (int i = 0; i < 2; ++i) {
                    int e = tid + (i << 8);
                    if (e < 320) { WsA[buf][e / 20][e % 20] = wr[i]; }
                }
            };
            float acc1 = 0.f, acc2 = 0.f;
            loadW(0); storeW(0);
            for (int c = 0; c < 32; ++c) {
                __syncthreads();
                if (c + 1 < 32) loadW(c + 1);
                const int buf = c & 1;
                const int k0 = c << 4;
#pragma unroll
                for (int kk = 0; kk < 16; ++kk) {
                    float w1 = WsA[buf][kk][cA];
                    acc1 += AT[rA][k0 + kk] * w1;
                    if (tid < 48) acc2 += AT[rA2][k0 + kk] * WsA[buf][kk][cA2];
                }
                if (c + 1 < 32) storeW((c + 1) & 1);
            }
            if (n0A + cA < 300)
                st_sc(&xt2[(size_t)(b0 + rA) * D2 + n0A + cA], 2.f * sigf(acc1) * aux1);
            if (tid < 48 && n0A + cA2 < 300)
                st_sc(&xt2[(size_t)(b0 + rA2) * D2 + n0A + cA2], 2.f * sigf(acc2) * aux2);
        }
        gbar(&bars[t * 3 + 0], tid);

        // ================= Phase B: ht2 = 2*sig(xt2@R) * ht ==================
        // stage xt2[b0..b0+15][0..299] -> AT cols 0..299, zero pad 300..303
#pragma unroll
        for (int i = 0; i < 5; ++i) {
            int e = tid + (i << 8);
            if (e < 1200) {
                int row = e / 75, c4 = (e % 75) << 2;
                const float* p = &xt2[(size_t)(b0 + row) * D2 + c4];
                float v0 = ld_sc(p), v1 = ld_sc(p + 1), v2 = ld_sc(p + 2), v3 = ld_sc(p + 3);
                AT[row][c4] = v0; AT[row][c4 + 1] = v1;
                AT[row][c4 + 2] = v2; AT[row][c4 + 3] = v3;
            }
        }
        if (tid < 64) AT[tid >> 2][300 + (tid & 3)] = 0.f;
        // prefetch aux = ht (pre-update value, cross-WG -> sc)
        float auxB0 = ld_sc(&ht[(size_t)(b0 + rB) * HH + h0 + cB2]);
        float auxB1 = ld_sc(&ht[(size_t)(b0 + rB) * HH + h0 + cB2 + 1]);

        {
            float wr[2];
            auto loadW = [&](int cblk) {
                const int k0 = cblk << 4;
#pragma unroll
                for (int i = 0; i < 2; ++i) {
                    int e = tid + (i << 8);
                    int kk = e >> 5, cc = e & 31;
                    wr[i] = (k0 + kk < 300) ? R[(size_t)(k0 + kk) * HH + h0 + cc] : 0.f;
                }
            };
            auto storeW = [&](int buf) {
#pragma unroll
                for (int i = 0; i < 2; ++i) {
                    int e = tid + (i << 8);
                    WsB[buf][e >> 5][e & 31] = wr[i];
                }
            };
            float acc0 = 0.f, acc1 = 0.f;
            loadW(0); storeW(0);
            for (int c = 0; c < 19; ++c) {
                __syncthreads();
                if (c + 1 < 19) loadW(c + 1);
                const int buf = c & 1;
                const int k0 = c << 4;
#pragma unroll
                for (int kk = 0; kk < 16; ++kk) {
                    float a = AT[rB][k0 + kk];
                    acc0 += a * WsB[buf][kk][cB2];
                    acc1 += a * WsB[buf][kk][cB2 + 1];
                }
                if (c + 1 < 19) storeW((c + 1) & 1);
            }
            st_sc(&ht2[(size_t)(b0 + rB) * HH + h0 + cB2], 2.f * sigf(acc0) * auxB0);
            st_sc(&ht2[(size_t)(b0 + rB) * HH + h0 + cB2 + 1], 2.f * sigf(acc1) * auxB1);
        }
        gbar(&bars[t * 3 + 1], tid);

        // ======= Phase C: gates = xt2@Wih + ht2@Whh + cell update ===========
        // xt2 already in AT cols 0..303; stage ht2 -> AT cols 304..815
#pragma unroll
        for (int i = 0; i < 8; ++i) {
            int e = tid + (i << 8);
            int row = e >> 7, c4 = (e & 127) << 2;
            const float* p = &ht2[(size_t)(b0 + row) * HH + c4];
            float v0 = ld_sc(p), v1 = ld_sc(p + 1), v2 = ld_sc(p + 2), v3 = ld_sc(p + 3);
            AT[row][304 + c4] = v0; AT[row][304 + c4 + 1] = v1;
            AT[row][304 + c4 + 2] = v2; AT[row][304 + c4 + 3] = v3;
        }
        {
            float rb[8];
            auto loadW = [&](int c) {
#pragma unroll
                for (int i = 0; i < 8; ++i) {
                    int e2 = tid + (i << 8);
                    int kk2 = e2 >> 7, cc = e2 & 127, s = cc >> 5, hh = cc & 31;
                    if (c < 19) {
                        int k = c * 16 + kk2;
                        rb[i] = (k < 300) ? Wih[(size_t)k * 2048 + s * 512 + h0 + hh] : 0.f;
                    } else {
                        int k = (c - 19) * 16 + kk2;
                        rb[i] = Whh[(size_t)k * 2048 + s * 512 + h0 + hh];
                    }
                }
            };
            auto storeW = [&](int buf) {
#pragma unroll
                for (int i = 0; i < 8; ++i) {
                    int e2 = tid + (i << 8);
                    int kk2 = e2 >> 7, cc = e2 & 127, s = cc >> 5, hh = cc & 31;
                    Bs[buf][kk2][s][hh] = rb[i];
                }
            };
            float acc[2][4] = {{0.f,0.f,0.f,0.f},{0.f,0.f,0.f,0.f}};
            loadW(0); storeW(0);
            for (int c = 0; c < 51; ++c) {
                __syncthreads();
                if (c + 1 < 51) loadW(c + 1);
                const int buf = c & 1;
                const int kbase = (c < 19) ? (c * 16) : (304 + (c - 19) * 16);
#pragma unroll
                for (int kk = 0; kk < 16; ++kk) {
                    float a0 = AT[2 * rp][kbase + kk];
                    float a1 = AT[2 * rp + 1][kbase + kk];
                    float b0v = Bs[buf][kk][0][hx];
                    float b1v = Bs[buf][kk][1][hx];
                    float b2v = Bs[buf][kk][2][hx];
                    float b3v = Bs[buf][kk][3][hx];
                    acc[0][0] += a0 * b0v; acc[0][1] += a0 * b1v;
                    acc[0][2] += a0 * b2v; acc[0][3] += a0 * b3v;
                    acc[1][0] += a1 * b0v; acc[1][1] += a1 * b1v;
                    acc[1][2] += a1 * b2v; acc[1][3] += a1 * b3v;
                }
                if (c + 1 < 51) storeW((c + 1) & 1);
            }
#pragma unroll
            for (int j = 0; j < 2; ++j) {
                const int r = b0 + rp * 2 + j;
                const float ig = acc[j][0] + bi0;
                const float fg = acc[j][1] + bi1;
                const float gg = acc[j][2] + bi2;
                const float og = acc[j][3] + bi3;
                const float cn = sigf(fg) * ct_reg[j] + sigf(ig) * tanhf(gg);
                const float hn = sigf(og) * tanhf(cn);
                ct_reg[j] = cn;
                st_sc(&ht[(size_t)r * HH + h], hn);
                hseq[((size_t)r * SS + t) * HH + h] = __float2bfloat16(hn);
            }
        }
        gbar(&bars[t * 3 + 2], tid);
    }
}

// ---------------------------------------------------------------------------
// Conv + relu + maxpool over time. One WG per batch row. hseq is bf16.
// ---------------------------------------------------------------------------
__global__ __launch_bounds__(256) void conv_kernel(
    const __hip_bfloat16* __restrict__ hseq,
    const float* __restrict__ w3, const float* __restrict__ cb3,
    const float* __restrict__ w4, const float* __restrict__ cb4,
    const float* __restrict__ w5, const float* __restrict__ cb5,
    float* __restrict__ feats)
{
    __shared__ float sh[20 * 516];
    __shared__ float part[16 * 16 * 9];
    __shared__ int rmax[9];
    const int b = blockIdx.x;
    const int tid = threadIdx.x;
    if (tid < 9) rmax[tid] = 0;
    const int wv = tid >> 6, lane = tid & 63;
    const int t0l = lane >> 2, hs = lane & 3;

    for (int p = 0; p < 16; ++p) {
        __syncthreads();
#pragma unroll
        for (int i = 0; i < 5; ++i) {
            int e = tid + (i << 8);
            int row = e >> 6, q = e & 63;
            int tg = p * 16 + row;
            float v[8];
            if (tg < SS) {
                uint4 u = *(const uint4*)(hseq + (((size_t)b * SS + tg) << 9) + (q << 3));
                v[0] = __uint_as_float(u.x << 16); v[1] = __uint_as_float(u.x & 0xffff0000u);
                v[2] = __uint_as_float(u.y << 16); v[3] = __uint_as_float(u.y & 0xffff0000u);
                v[4] = __uint_as_float(u.z << 16); v[5] = __uint_as_float(u.z & 0xffff0000u);
                v[6] = __uint_as_float(u.w << 16); v[7] = __uint_as_float(u.w & 0xffff0000u);
            } else {
#pragma unroll
                for (int j = 0; j < 8; ++j) v[j] = 0.f;
            }
#pragma unroll
            for (int j = 0; j < 8; ++j) sh[row * 516 + q * 8 + j] = v[j];
        }
        __syncthreads();

        float acc[9];
#pragma unroll
        for (int j = 0; j < 9; ++j) acc[j] = 0.f;
        for (int k = 0; k < 32; ++k) {
            const int hcol = (wv << 7) + (k << 2) + hs;
            const float v0 = sh[(t0l + 0) * 516 + hcol];
            const float v1 = sh[(t0l + 1) * 516 + hcol];
            const float v2 = sh[(t0l + 2) * 516 + hcol];
            const float v3 = sh[(t0l + 3) * 516 + hcol];
            const float v4 = sh[(t0l + 4) * 516 + hcol];
#pragma unroll
            for (int f = 0; f < 3; ++f) {
                acc[f]     += v0 * w3[(f * 3 + 0) * 512 + hcol] + v1 * w3[(f * 3 + 1) * 512 + hcol]
                            + v2 * w3[(f * 3 + 2) * 512 + hcol];
                acc[3 + f] += v0 * w4[(f * 4 + 0) * 512 + hcol] + v1 * w4[(f * 4 + 1) * 512 + hcol]
                            + v2 * w4[(f * 4 + 2) * 512 + hcol] + v3 * w4[(f * 4 + 3) * 512 + hcol];
                acc[6 + f] += v0 * w5[(f * 5 + 0) * 512 + hcol] + v1 * w5[(f * 5 + 1) * 512 + hcol]
                            + v2 * w5[(f * 5 + 2) * 512 + hcol] + v3 * w5[(f * 5 + 3) * 512 + hcol]
                            + v4 * w5[(f * 5 + 4) * 512 + hcol];
            }
        }
        const int pi = (wv << 2) + hs;
#pragma unroll
        for (int j = 0; j < 9; ++j) part[(pi * 16 + t0l) * 9 + j] = acc[j];
        __syncthreads();
        if (tid < 144) {
            const int tl = tid / 9, j = tid % 9;
            float s = 0.f;
#pragma unroll
            for (int pp = 0; pp < 16; ++pp) s += part[(pp * 16 + tl) * 9 + j];
            const int fsz = j < 3 ? 3 : (j < 6 ? 4 : 5);
            const int t0 = p * 16 + tl;
            if (t0 <= SS - fsz) {
                const float bias = j < 3 ? cb3[j] : (j < 6 ? cb4[j - 3] : cb5[j - 6]);
                float v = s + bias;
                v = v > 0.f ? v : 0.f;
                atomicMax(&rmax[j], __float_as_int(v));
            }
        }
    }
    __syncthreads();
    if (tid < 9) feats[b * 9 + tid] = __int_as_float(rmax[tid]);
}

__global__ void final_kernel(const float* __restrict__ feats,
                             const float* __restrict__ lin_w,
                             const float* __restrict__ lin_b,
                             float* __restrict__ out)
{
    const int b = threadIdx.x;
    float o0 = lin_b[0], o1 = lin_b[1];
#pragma unroll
    for (int j = 0; j < 9; ++j) {
        const float f = feats[b * 9 + j];
        o0 += f * lin_w[j * 2 + 0];
        o1 += f * lin_w[j * 2 + 1];
    }
    out[b * 2 + 0] = o0;
    out[b * 2 + 1] = o1;
}

extern "C" void kernel_launch(void* const* d_in, const int* in_sizes, int n_in,
                              void* d_out, int out_size, void* d_ws, size_t ws_size,
                              hipStream_t stream) {
    const float* x    = (const float*)d_in[0];
    const float* W_in = (const float*)d_in[1];
    const float* b_in = (const float*)d_in[2];
    const float* Wih  = (const float*)d_in[3];
    const float* Whh  = (const float*)d_in[4];
    const float* bih  = (const float*)d_in[5];
    const float* bhh  = (const float*)d_in[6];
    const float* Q    = (const float*)d_in[7];
    const float* R    = (const float*)d_in[8];
    const float* lin_w = (const float*)d_in[9];
    const float* lin_b = (const float*)d_in[10];
    const float* w3 = (const float*)d_in[11];
    const float* cb3 = (const float*)d_in[12];
    const float* w4 = (const float*)d_in[13];
    const float* cb4 = (const float*)d_in[14];
    const float* w5 = (const float*)d_in[15];
    const float* cb5 = (const float*)d_in[16];

    float* ws = (float*)d_ws;
    float* xp    = ws;                              // [S][B][300]
    float* xt2   = xp + (size_t)BB * SS * D2;
    float* ht    = xt2 + BB * D2;
    float* ht2   = ht + BB * HH;
    float* feats = ht2 + BB * HH;
    __hip_bfloat16* hseq = (__hip_bfloat16*)(feats + BB * 9);
    int* bars = (int*)(hseq + (size_t)BB * SS * HH);   // 768 ints

    xp_kernel<<<dim3(5, 2048), 256, 0, stream>>>(x, W_in, b_in, xp);

    void* args[] = {(void*)&xp, (void*)&Q, (void*)&R, (void*)&Wih, (void*)&Whh,
                    (void*)&bih, (void*)&bhh, (void*)&xt2, (void*)&ht, (void*)&ht2,
                    (void*)&hseq, (void*)&bars};
    hipLaunchCooperativeKernel((const void*)scan_kernel, dim3(256), dim3(256),
                               args, 0, stream);

    conv_kernel<<<dim3(256), 256, 0, stream>>>(hseq, w3, cb3, w4, cb4, w5, cb5, feats);
    final_kernel<<<dim3(1), 256, 0, stream>>>(feats, lin_w, lin_b, (float*)d_out);
}

// Round 5
// 30293.414 us; speedup vs baseline: 1.0085x; 1.0085x over previous
//
#include <hip/hip_runtime.h>
#include <hip/hip_bf16.h>
#include <hip/hip_cooperative_groups.h>
#include <math.h>

namespace cg = cooperative_groups;

#define BB 256
#define SS 256
#define DIN 300
#define D2 300
#define HH 512

__device__ __forceinline__ float sigf(float x) { return 1.0f / (1.0f + expf(-x)); }

// Cross-XCD coherent accesses (bypass non-coherent per-XCD L2, served by L3).
__device__ __forceinline__ float ld_sc(const float* p) {
    return __hip_atomic_load(p, __ATOMIC_RELAXED, __HIP_MEMORY_SCOPE_AGENT);
}
__device__ __forceinline__ void st_sc(float* p, float v) {
    __hip_atomic_store(p, v, __ATOMIC_RELAXED, __HIP_MEMORY_SCOPE_AGENT);
}

// Grid barrier: fresh counter per event; release-add publishes arrival after
// __syncthreads drains this WG's memory ops. No acquire -> no L2 invalidate,
// weights stay L2-resident.
__device__ __forceinline__ void gbar(int* cnt, int tid) {
    __syncthreads();
    if (tid == 0) {
        __hip_atomic_fetch_add(cnt, 1, __ATOMIC_RELEASE, __HIP_MEMORY_SCOPE_AGENT);
        while (__hip_atomic_load(cnt, __ATOMIC_RELAXED, __HIP_MEMORY_SCOPE_AGENT) < 256) {
            __builtin_amdgcn_s_sleep(1);
        }
    }
    __syncthreads();
}

// ---------------------------------------------------------------------------
// xp = tanh(x @ W_in + b_in), transposed to [S][B][D2].
// ---------------------------------------------------------------------------
__global__ __launch_bounds__(256) void xp_kernel(
    const float* __restrict__ A, const float* __restrict__ Bm,
    const float* __restrict__ bias, float* __restrict__ C)
{
    __shared__ float As[2][16][34];
    __shared__ float Bs[2][16][64];
    const int tid = threadIdx.x;
    const int m0 = blockIdx.y * 32;
    const int n0 = blockIdx.x * 64;
    const int tx = tid & 15;
    const int ty = tid >> 4;
    float acc[2][4] = {{0.f,0.f,0.f,0.f},{0.f,0.f,0.f,0.f}};
    const int NC = (DIN + 15) >> 4;

    float ra0, ra1, rb[4];
    auto load_regs = [&](int c) {
        const int k0 = c << 4;
        int e = tid, kk = e & 15, r = e >> 4;
        ra0 = (k0 + kk < DIN) ? A[(size_t)(m0 + r) * DIN + k0 + kk] : 0.f;
        e = tid + 256; kk = e & 15; r = e >> 4;
        ra1 = (k0 + kk < DIN) ? A[(size_t)(m0 + r) * DIN + k0 + kk] : 0.f;
#pragma unroll
        for (int i = 0; i < 4; ++i) {
            int e2 = tid + (i << 8);
            int kk2 = e2 >> 6, cc = e2 & 63;
            rb[i] = (k0 + kk2 < DIN && n0 + cc < D2) ? Bm[(k0 + kk2) * D2 + n0 + cc] : 0.f;
        }
    };
    auto store_lds = [&](int buf) {
        int e = tid; As[buf][e & 15][e >> 4] = ra0;
        e = tid + 256; As[buf][e & 15][e >> 4] = ra1;
#pragma unroll
        for (int i = 0; i < 4; ++i) {
            int e2 = tid + (i << 8);
            Bs[buf][e2 >> 6][e2 & 63] = rb[i];
        }
    };

    load_regs(0); store_lds(0);
    for (int c = 0; c < NC; ++c) {
        __syncthreads();
        if (c + 1 < NC) load_regs(c + 1);
        const int buf = c & 1;
#pragma unroll
        for (int kk = 0; kk < 16; ++kk) {
            float2 a = *(const float2*)&As[buf][kk][ty * 2];
            float4 b = *(const float4*)&Bs[buf][kk][tx * 4];
            acc[0][0] += a.x * b.x; acc[0][1] += a.x * b.y;
            acc[0][2] += a.x * b.z; acc[0][3] += a.x * b.w;
            acc[1][0] += a.y * b.x; acc[1][1] += a.y * b.y;
            acc[1][2] += a.y * b.z; acc[1][3] += a.y * b.w;
        }
        if (c + 1 < NC) store_lds((c + 1) & 1);
    }

#pragma unroll
    for (int j = 0; j < 2; ++j) {
        const int r = m0 + ty * 2 + j;
        const int b = r >> 8;
        const int s = r & 255;
#pragma unroll
        for (int i = 0; i < 4; ++i) {
            const int col = n0 + tx * 4 + i;
            if (col < D2) {
                C[((size_t)s * BB + b) * D2 + col] = tanhf(acc[j][i] + bias[col]);
            }
        }
    }
}

// ---------------------------------------------------------------------------
// Persistent scan. 256 WGs x 256 threads, 1/CU.
// XCD-aware tiling: xcd = w&7 (round-robin heuristic); WGs on one XCD use
// only 2 of the 16 column slices -> per-XCD weight working set < 1 MB,
// L2-resident. b0 = 16 batch rows owned in ALL phases (A staged once in LDS).
// ---------------------------------------------------------------------------
__global__ __launch_bounds__(256, 1) void scan_kernel(
    const float* __restrict__ xp,   // [S][B][D2]
    const float* __restrict__ Q, const float* __restrict__ R,
    const float* __restrict__ Wih, const float* __restrict__ Whh,
    const float* __restrict__ bih, const float* __restrict__ bhh,
    float* __restrict__ xt2, float* __restrict__ ht, float* __restrict__ ht2,
    __hip_bfloat16* __restrict__ hseq, int* __restrict__ bars)
{
    cg::grid_group grid = cg::this_grid();
    // AT: phase A: ht[16][512] cols 0..511; phase B: xt2[16][304] cols 0..303
    // (kept for phase C); phase C: ht2[16][512] cols 304..815.
    __shared__ float AT[16][820];               // 52.5 KB
    __shared__ float WsA[2][16][20];
    __shared__ float WsB[2][16][32];
    __shared__ float Bs[2][16][4][34];          // stride 34: b64-aligned pairs
    __shared__ float Gt[16][4][33];             // gate-seg transpose scratch

    const int w = blockIdx.x;
    const int tid = threadIdx.x;
    const int xcd = w & 7;
    const int g = w >> 3;               // 0..31
    const int cs = xcd * 2 + (g & 1);   // column slice 0..15, 2 per XCD
    const int b0 = (g >> 1) * 16;       // batch-row block 0..15
    const int n0A = cs * 19;            // phase A cols (19 wide, clipped at 300)
    const int h0  = cs * 32;            // phase B/C col slice

    // ---- init: zero ht slice, barrier counters; ct lives in registers.
    {
        int e = tid * 2;
        int r = e >> 5, c = e & 31;
        st_sc(&ht[(size_t)(b0 + r) * HH + h0 + c], 0.f);
        st_sc(&ht[(size_t)(b0 + r) * HH + h0 + c + 1], 0.f);
        if (tid < 3) {
            __hip_atomic_store(&bars[w * 3 + tid], 0, __ATOMIC_RELAXED,
                               __HIP_MEMORY_SCOPE_AGENT);
        }
    }
    float ct_reg[2] = {0.f, 0.f};

    // Phase A mapping: 16x19 = 304 outputs; threads 0..255 + threads 0..47 again
    const int rA = tid / 19, cA = tid % 19;
    const int rA2 = (tid + 256) / 19, cA2 = (tid + 256) % 19;
    // Phase B mapping: 16 rows x 32 cols, 2 cols/thread
    const int rB = tid >> 4, cB2 = (tid & 15) * 2;
    // Phase C GEMM mapping: 4 rows x 1 seg x 2 cols per thread
    const int rgrp = tid >> 6;          // 0..3 (wave-uniform)
    const int segC = (tid >> 4) & 3;
    const int hxp = tid & 15;
    // Phase C epilogue mapping (2 rows per thread; owns ct_reg)
    const int hx = tid & 31;
    const int rp = tid >> 5;
    const int h = h0 + hx;
    const float bi0 = bih[h] + bhh[h];
    const float bi1 = bih[512 + h] + bhh[512 + h];
    const float bi2 = bih[1024 + h] + bhh[1024 + h];
    const float bi3 = bih[1536 + h] + bhh[1536 + h];

    grid.sync();

    for (int t = 0; t < SS; ++t) {
        const float* xpt = xp + (size_t)t * BB * D2;

        // ================= Phase A: xt2 = 2*sig(ht@Q) * xp_t =================
#pragma unroll
        for (int i = 0; i < 8; ++i) {
            int e = tid + (i << 8);
            int row = e >> 7, c4 = (e & 127) << 2;
            const float* p = &ht[(size_t)(b0 + row) * HH + c4];
            float v0 = ld_sc(p), v1 = ld_sc(p + 1), v2 = ld_sc(p + 2), v3 = ld_sc(p + 3);
            AT[row][c4] = v0; AT[row][c4 + 1] = v1;
            AT[row][c4 + 2] = v2; AT[row][c4 + 3] = v3;
        }
        float aux1 = (n0A + cA < 300) ? xpt[(b0 + rA) * D2 + n0A + cA] : 0.f;
        float aux2 = (tid < 48 && n0A + cA2 < 300) ? xpt[(b0 + rA2) * D2 + n0A + cA2] : 0.f;

        {
            float wr[2];
            auto loadW = [&](int cblk) {
                const int k0 = cblk << 4;
#pragma unroll
                for (int i = 0; i < 2; ++i) {
                    int e = tid + (i << 8);
                    wr[i] = 0.f;
                    if (e < 320) {
                        int kk = e / 20, cc = e % 20;
                        if (cc < 19 && n0A + cc < 300)
                            wr[i] = Q[(size_t)(k0 + kk) * D2 + n0A + cc];
                    }
                }
            };
            auto storeW = [&](int buf) {
#pragma unroll
                for (int i = 0; i < 2; ++i) {
                    int e = tid + (i << 8);
                    if (e < 320) { WsA[buf][e / 20][e % 20] = wr[i]; }
                }
            };
            float acc1 = 0.f, acc2 = 0.f;
            loadW(0); storeW(0);
            for (int c = 0; c < 32; ++c) {
                __syncthreads();
                if (c + 1 < 32) loadW(c + 1);
                const int buf = c & 1;
                const int k0 = c << 4;
#pragma unroll
                for (int kk = 0; kk < 16; ++kk) {
                    acc1 += AT[rA][k0 + kk] * WsA[buf][kk][cA];
                    if (tid < 48) acc2 += AT[rA2][k0 + kk] * WsA[buf][kk][cA2];
                }
                if (c + 1 < 32) storeW((c + 1) & 1);
            }
            if (n0A + cA < 300)
                st_sc(&xt2[(size_t)(b0 + rA) * D2 + n0A + cA], 2.f * sigf(acc1) * aux1);
            if (tid < 48 && n0A + cA2 < 300)
                st_sc(&xt2[(size_t)(b0 + rA2) * D2 + n0A + cA2], 2.f * sigf(acc2) * aux2);
        }
        gbar(&bars[t * 3 + 0], tid);

        // ================= Phase B: ht2 = 2*sig(xt2@R) * ht ==================
#pragma unroll
        for (int i = 0; i < 5; ++i) {
            int e = tid + (i << 8);
            if (e < 1200) {
                int row = e / 75, c4 = (e % 75) << 2;
                const float* p = &xt2[(size_t)(b0 + row) * D2 + c4];
                float v0 = ld_sc(p), v1 = ld_sc(p + 1), v2 = ld_sc(p + 2), v3 = ld_sc(p + 3);
                AT[row][c4] = v0; AT[row][c4 + 1] = v1;
                AT[row][c4 + 2] = v2; AT[row][c4 + 3] = v3;
            }
        }
        if (tid < 64) AT[tid >> 2][300 + (tid & 3)] = 0.f;
        float auxB0 = ld_sc(&ht[(size_t)(b0 + rB) * HH + h0 + cB2]);
        float auxB1 = ld_sc(&ht[(size_t)(b0 + rB) * HH + h0 + cB2 + 1]);

        {
            float wr[2];
            auto loadW = [&](int cblk) {
                const int k0 = cblk << 4;
#pragma unroll
                for (int i = 0; i < 2; ++i) {
                    int e = tid + (i << 8);
                    int kk = e >> 5, cc = e & 31;
                    wr[i] = (k0 + kk < 300) ? R[(size_t)(k0 + kk) * HH + h0 + cc] : 0.f;
                }
            };
            auto storeW = [&](int buf) {
#pragma unroll
                for (int i = 0; i < 2; ++i) {
                    int e = tid + (i << 8);
                    WsB[buf][e >> 5][e & 31] = wr[i];
                }
            };
            float acc0 = 0.f, acc1 = 0.f;
            loadW(0); storeW(0);
            for (int c = 0; c < 19; ++c) {
                __syncthreads();
                if (c + 1 < 19) loadW(c + 1);
                const int buf = c & 1;
                const int k0 = c << 4;
#pragma unroll
                for (int kk = 0; kk < 16; ++kk) {
                    float a = AT[rB][k0 + kk];
                    acc0 += a * WsB[buf][kk][cB2];
                    acc1 += a * WsB[buf][kk][cB2 + 1];
                }
                if (c + 1 < 19) storeW((c + 1) & 1);
            }
            st_sc(&ht2[(size_t)(b0 + rB) * HH + h0 + cB2], 2.f * sigf(acc0) * auxB0);
            st_sc(&ht2[(size_t)(b0 + rB) * HH + h0 + cB2 + 1], 2.f * sigf(acc1) * auxB1);
        }
        gbar(&bars[t * 3 + 1], tid);

        // ======= Phase C: gates = xt2@Wih + ht2@Whh + cell update ===========
        // xt2 already in AT cols 0..303; stage ht2 -> AT cols 304..815
#pragma unroll
        for (int i = 0; i < 8; ++i) {
            int e = tid + (i << 8);
            int row = e >> 7, c4 = (e & 127) << 2;
            const float* p = &ht2[(size_t)(b0 + row) * HH + c4];
            float v0 = ld_sc(p), v1 = ld_sc(p + 1), v2 = ld_sc(p + 2), v3 = ld_sc(p + 3);
            AT[row][304 + c4] = v0; AT[row][304 + c4 + 1] = v1;
            AT[row][304 + c4 + 2] = v2; AT[row][304 + c4 + 3] = v3;
        }
        {
            float rb[8];
            auto loadW = [&](int c) {
#pragma unroll
                for (int i = 0; i < 8; ++i) {
                    int e2 = tid + (i << 8);
                    int kk2 = e2 >> 7, cc = e2 & 127, s = cc >> 5, hh = cc & 31;
                    if (c < 19) {
                        int k = c * 16 + kk2;
                        rb[i] = (k < 300) ? Wih[(size_t)k * 2048 + s * 512 + h0 + hh] : 0.f;
                    } else {
                        int k = (c - 19) * 16 + kk2;
                        rb[i] = Whh[(size_t)k * 2048 + s * 512 + h0 + hh];
                    }
                }
            };
            auto storeW = [&](int buf) {
#pragma unroll
                for (int i = 0; i < 8; ++i) {
                    int e2 = tid + (i << 8);
                    int kk2 = e2 >> 7, cc = e2 & 127, s = cc >> 5, hh = cc & 31;
                    Bs[buf][kk2][s][hh] = rb[i];
                }
            };
            float accC[4][2] = {{0.f,0.f},{0.f,0.f},{0.f,0.f},{0.f,0.f}};
            loadW(0); storeW(0);
            for (int c = 0; c < 51; ++c) {
                __syncthreads();
                if (c + 1 < 51) loadW(c + 1);
                const int buf = c & 1;
                const int kbase = (c < 19) ? (c * 16) : (304 + (c - 19) * 16);
#pragma unroll
                for (int kk = 0; kk < 16; ++kk) {
                    float2 b2 = *(const float2*)&Bs[buf][kk][segC][hxp * 2];
#pragma unroll
                    for (int j = 0; j < 4; ++j) {
                        float a = AT[rgrp * 4 + j][kbase + kk];
                        accC[j][0] += a * b2.x;
                        accC[j][1] += a * b2.y;
                    }
                }
                if (c + 1 < 51) storeW((c + 1) & 1);
            }
            // transpose gate segs through LDS for the cell update
#pragma unroll
            for (int j = 0; j < 4; ++j) {
                Gt[rgrp * 4 + j][segC][hxp * 2]     = accC[j][0];
                Gt[rgrp * 4 + j][segC][hxp * 2 + 1] = accC[j][1];
            }
            __syncthreads();
#pragma unroll
            for (int j = 0; j < 2; ++j) {
                const int row = rp * 2 + j;
                const int r = b0 + row;
                const float ig = Gt[row][0][hx] + bi0;
                const float fg = Gt[row][1][hx] + bi1;
                const float gg = Gt[row][2][hx] + bi2;
                const float og = Gt[row][3][hx] + bi3;
                const float cn = sigf(fg) * ct_reg[j] + sigf(ig) * tanhf(gg);
                const float hn = sigf(og) * tanhf(cn);
                ct_reg[j] = cn;
                st_sc(&ht[(size_t)r * HH + h], hn);
                hseq[((size_t)r * SS + t) * HH + h] = __float2bfloat16(hn);
            }
        }
        gbar(&bars[t * 3 + 2], tid);
    }
}

// ---------------------------------------------------------------------------
// Conv + relu + maxpool over time. One WG per batch row. hseq is bf16.
// ---------------------------------------------------------------------------
__global__ __launch_bounds__(256) void conv_kernel(
    const __hip_bfloat16* __restrict__ hseq,
    const float* __restrict__ w3, const float* __restrict__ cb3,
    const float* __restrict__ w4, const float* __restrict__ cb4,
    const float* __restrict__ w5, const float* __restrict__ cb5,
    float* __restrict__ feats)
{
    __shared__ float sh[20 * 516];
    __shared__ float part[16 * 16 * 9];
    __shared__ int rmax[9];
    const int b = blockIdx.x;
    const int tid = threadIdx.x;
    if (tid < 9) rmax[tid] = 0;
    const int wv = tid >> 6, lane = tid & 63;
    const int t0l = lane >> 2, hs = lane & 3;

    for (int p = 0; p < 16; ++p) {
        __syncthreads();
#pragma unroll
        for (int i = 0; i < 5; ++i) {
            int e = tid + (i << 8);
            int row = e >> 6, q = e & 63;
            int tg = p * 16 + row;
            float v[8];
            if (tg < SS) {
                uint4 u = *(const uint4*)(hseq + (((size_t)b * SS + tg) << 9) + (q << 3));
                v[0] = __uint_as_float(u.x << 16); v[1] = __uint_as_float(u.x & 0xffff0000u);
                v[2] = __uint_as_float(u.y << 16); v[3] = __uint_as_float(u.y & 0xffff0000u);
                v[4] = __uint_as_float(u.z << 16); v[5] = __uint_as_float(u.z & 0xffff0000u);
                v[6] = __uint_as_float(u.w << 16); v[7] = __uint_as_float(u.w & 0xffff0000u);
            } else {
#pragma unroll
                for (int j = 0; j < 8; ++j) v[j] = 0.f;
            }
#pragma unroll
            for (int j = 0; j < 8; ++j) sh[row * 516 + q * 8 + j] = v[j];
        }
        __syncthreads();

        float acc[9];
#pragma unroll
        for (int j = 0; j < 9; ++j) acc[j] = 0.f;
        for (int k = 0; k < 32; ++k) {
            const int hcol = (wv << 7) + (k << 2) + hs;
            const float v0 = sh[(t0l + 0) * 516 + hcol];
            const float v1 = sh[(t0l + 1) * 516 + hcol];
            const float v2 = sh[(t0l + 2) * 516 + hcol];
            const float v3 = sh[(t0l + 3) * 516 + hcol];
            const float v4 = sh[(t0l + 4) * 516 + hcol];
#pragma unroll
            for (int f = 0; f < 3; ++f) {
                acc[f]     += v0 * w3[(f * 3 + 0) * 512 + hcol] + v1 * w3[(f * 3 + 1) * 512 + hcol]
                            + v2 * w3[(f * 3 + 2) * 512 + hcol];
                acc[3 + f] += v0 * w4[(f * 4 + 0) * 512 + hcol] + v1 * w4[(f * 4 + 1) * 512 + hcol]
                            + v2 * w4[(f * 4 + 2) * 512 + hcol] + v3 * w4[(f * 4 + 3) * 512 + hcol];
                acc[6 + f] += v0 * w5[(f * 5 + 0) * 512 + hcol] + v1 * w5[(f * 5 + 1) * 512 + hcol]
                            + v2 * w5[(f * 5 + 2) * 512 + hcol] + v3 * w5[(f * 5 + 3) * 512 + hcol]
                            + v4 * w5[(f * 5 + 4) * 512 + hcol];
            }
        }
        const int pi = (wv << 2) + hs;
#pragma unroll
        for (int j = 0; j < 9; ++j) part[(pi * 16 + t0l) * 9 + j] = acc[j];
        __syncthreads();
        if (tid < 144) {
            const int tl = tid / 9, j = tid % 9;
            float s = 0.f;
#pragma unroll
            for (int pp = 0; pp < 16; ++pp) s += part[(pp * 16 + tl) * 9 + j];
            const int fsz = j < 3 ? 3 : (j < 6 ? 4 : 5);
            const int t0 = p * 16 + tl;
            if (t0 <= SS - fsz) {
                const float bias = j < 3 ? cb3[j] : (j < 6 ? cb4[j - 3] : cb5[j - 6]);
                float v = s + bias;
                v = v > 0.f ? v : 0.f;
                atomicMax(&rmax[j], __float_as_int(v));
            }
        }
    }
    __syncthreads();
    if (tid < 9) feats[b * 9 + tid] = __int_as_float(rmax[tid]);
}

__global__ void final_kernel(const float* __restrict__ feats,
                             const float* __restrict__ lin_w,
                             const float* __restrict__ lin_b,
                             float* __restrict__ out)
{
    const int b = threadIdx.x;
    float o0 = lin_b[0], o1 = lin_b[1];
#pragma unroll
    for (int j = 0; j < 9; ++j) {
        const float f = feats[b * 9 + j];
        o0 += f * lin_w[j * 2 + 0];
        o1 += f * lin_w[j * 2 + 1];
    }
    out[b * 2 + 0] = o0;
    out[b * 2 + 1] = o1;
}

extern "C" void kernel_launch(void* const* d_in, const int* in_sizes, int n_in,
                              void* d_out, int out_size, void* d_ws, size_t ws_size,
                              hipStream_t stream) {
    const float* x    = (const float*)d_in[0];
    const float* W_in = (const float*)d_in[1];
    const float* b_in = (const float*)d_in[2];
    const float* Wih  = (const float*)d_in[3];
    const float* Whh  = (const float*)d_in[4];
    const float* bih  = (const float*)d_in[5];
    const float* bhh  = (const float*)d_in[6];
    const float* Q    = (const float*)d_in[7];
    const float* R    = (const float*)d_in[8];
    const float* lin_w = (const float*)d_in[9];
    const float* lin_b = (const float*)d_in[10];
    const float* w3 = (const float*)d_in[11];
    const float* cb3 = (const float*)d_in[12];
    const float* w4 = (const float*)d_in[13];
    const float* cb4 = (const float*)d_in[14];
    const float* w5 = (const float*)d_in[15];
    const float* cb5 = (const float*)d_in[16];

    float* ws = (float*)d_ws;
    float* xp    = ws;                              // [S][B][300]
    float* xt2   = xp + (size_t)BB * SS * D2;
    float* ht    = xt2 + BB * D2;
    float* ht2   = ht + BB * HH;
    float* feats = ht2 + BB * HH;
    __hip_bfloat16* hseq = (__hip_bfloat16*)(feats + BB * 9);
    int* bars = (int*)(hseq + (size_t)BB * SS * HH);   // 768 ints

    xp_kernel<<<dim3(5, 2048), 256, 0, stream>>>(x, W_in, b_in, xp);

    void* args[] = {(void*)&xp, (void*)&Q, (void*)&R, (void*)&Wih, (void*)&Whh,
                    (void*)&bih, (void*)&bhh, (void*)&xt2, (void*)&ht, (void*)&ht2,
                    (void*)&hseq, (void*)&bars};
    hipLaunchCooperativeKernel((const void*)scan_kernel, dim3(256), dim3(256),
                               args, 0, stream);

    conv_kernel<<<dim3(256), 256, 0, stream>>>(hseq, w3, cb3, w4, cb4, w5, cb5, feats);
    final_kernel<<<dim3(1), 256, 0, stream>>>(feats, lin_w, lin_b, (float*)d_out);
}